// Round 1
// baseline (866.660 us; speedup 1.0000x reference)
//
#include <hip/hip_runtime.h>

#define NN 50000
#define NE 800000
#define KD 256
#define CD 128

// ---------------------------------------------------------------- deg init
__global__ __launch_bounds__(256) void init_deg(float* __restrict__ deg) {
    int i = blockIdx.x * 256 + threadIdx.x;
    if (i < NN) deg[i] = 1.0f;  // self-loop weight
}

// ------------------------------------------------------------- deg scatter
__global__ __launch_bounds__(256) void deg_scatter(const int* __restrict__ col,
                                                   const float* __restrict__ ew,
                                                   float* __restrict__ deg) {
    int e = blockIdx.x * 256 + threadIdx.x;
    if (e < NE) unsafeAtomicAdd(&deg[col[e]], ew[e]);
}

// ---------------------------------------------------------------- rsqrt
__global__ __launch_bounds__(256) void rsqrt_deg(const float* __restrict__ deg,
                                                 float* __restrict__ dinv) {
    int i = blockIdx.x * 256 + threadIdx.x;
    if (i < NN) dinv[i] = rsqrtf(deg[i]);  // deg >= 1 always
}

// ------------------------------------------------- h = x @ W  (fp32 tiled)
// BM=64 nodes, BN=128 (all channels), BK=32. 256 threads, each 4x8 outputs.
__global__ __launch_bounds__(256) void gemm_xw(const float* __restrict__ x,
                                               const float* __restrict__ Wm,
                                               float* __restrict__ h) {
    __shared__ float As[64][33];    // [node][k], +1 pad
    __shared__ float Bs[32][132];   // [k][ch],  +4 pad (keeps 16B align)

    const int tid = threadIdx.x;
    const int ty  = tid >> 4;    // 0..15 -> node group of 4
    const int tx  = tid & 15;    // 0..15 -> ch group of 8
    const int row0 = blockIdx.x * 64;

    const int arow = tid >> 2;   // 0..63
    const int akq  = tid & 3;    // 0..3
    const int brow = tid >> 3;   // 0..31
    const int bcol = tid & 7;    // 0..7

    float acc[4][8];
#pragma unroll
    for (int i = 0; i < 4; i++)
#pragma unroll
        for (int j = 0; j < 8; j++) acc[i][j] = 0.0f;

    for (int kt = 0; kt < KD; kt += 32) {
        // ---- stage A tile (64 x 32)
        int anode = row0 + arow;
        float4 av0 = make_float4(0.f, 0.f, 0.f, 0.f), av1 = av0;
        if (anode < NN) {
            const float* xp = x + (size_t)anode * KD + kt;
            av0 = *(const float4*)(xp + akq * 4);
            av1 = *(const float4*)(xp + akq * 4 + 16);
        }
        As[arow][akq * 4 + 0]  = av0.x; As[arow][akq * 4 + 1]  = av0.y;
        As[arow][akq * 4 + 2]  = av0.z; As[arow][akq * 4 + 3]  = av0.w;
        As[arow][akq * 4 + 16] = av1.x; As[arow][akq * 4 + 17] = av1.y;
        As[arow][akq * 4 + 18] = av1.z; As[arow][akq * 4 + 19] = av1.w;
        // ---- stage B tile (32 x 128)
        const float* wp = Wm + (size_t)(kt + brow) * CD;
#pragma unroll
        for (int q = 0; q < 4; q++) {
            float4 bv = *(const float4*)(wp + (q * 8 + bcol) * 4);
            *(float4*)&Bs[brow][(q * 8 + bcol) * 4] = bv;
        }
        __syncthreads();
        // ---- inner product
#pragma unroll
        for (int k = 0; k < 32; k++) {
            float aa[4];
#pragma unroll
            for (int i = 0; i < 4; i++) aa[i] = As[ty * 4 + i][k];
            float4 b0 = *(const float4*)&Bs[k][tx * 8];
            float4 b1 = *(const float4*)&Bs[k][tx * 8 + 4];
            float bb[8] = {b0.x, b0.y, b0.z, b0.w, b1.x, b1.y, b1.z, b1.w};
#pragma unroll
            for (int i = 0; i < 4; i++)
#pragma unroll
                for (int j = 0; j < 8; j++)
                    acc[i][j] = fmaf(aa[i], bb[j], acc[i][j]);
        }
        __syncthreads();
    }

#pragma unroll
    for (int i = 0; i < 4; i++) {
        int node = row0 + ty * 4 + i;
        if (node < NN) {
            float* hp = h + (size_t)node * CD + tx * 8;
            *(float4*)hp       = make_float4(acc[i][0], acc[i][1], acc[i][2], acc[i][3]);
            *(float4*)(hp + 4) = make_float4(acc[i][4], acc[i][5], acc[i][6], acc[i][7]);
        }
    }
}

// ------------------------------------------- edge scatter: one wave / edge
__global__ __launch_bounds__(256) void edge_scatter(const int* __restrict__ row,
                                                    const int* __restrict__ col,
                                                    const float* __restrict__ ew,
                                                    const float* __restrict__ dinv,
                                                    const float* __restrict__ h,
                                                    float* __restrict__ out) {
    int e = blockIdx.x * 4 + (threadIdx.x >> 6);
    if (e >= NE) return;
    e = __builtin_amdgcn_readfirstlane(e);   // force scalar loads of edge data
    const int lane = threadIdx.x & 63;
    const int r = row[e];
    const int c = col[e];
    const float nrm = dinv[r] * ew[e] * dinv[c];
    float2 v = *(const float2*)(h + (size_t)r * CD + lane * 2);
    float* op = out + (size_t)c * CD + lane * 2;
    unsafeAtomicAdd(op,     v.x * nrm);
    unsafeAtomicAdd(op + 1, v.y * nrm);
}

// ------------------------- epilogue: + self-loop + bias, PReLU, in place
__global__ __launch_bounds__(256) void epilogue(float* __restrict__ out,
                                                const float* __restrict__ h,
                                                const float* __restrict__ dinv,
                                                const float* __restrict__ bias,
                                                const float* __restrict__ alpha) {
    int i = blockIdx.x * 256 + threadIdx.x;  // float4 index
    const int total = NN * (CD / 4);
    if (i >= total) return;
    int node = i >> 5;       // 32 float4 per row
    int cq   = i & 31;
    float s  = dinv[node];
    float s2 = s * s;
    float4 o  = ((float4*)out)[i];
    float4 hv = ((const float4*)h)[i];
    float4 bv = ((const float4*)bias)[cq];
    float4 av = ((const float4*)alpha)[cq];
    o.x += hv.x * s2 + bv.x;
    o.y += hv.y * s2 + bv.y;
    o.z += hv.z * s2 + bv.z;
    o.w += hv.w * s2 + bv.w;
    o.x = o.x >= 0.f ? o.x : av.x * o.x;
    o.y = o.y >= 0.f ? o.y : av.y * o.y;
    o.z = o.z >= 0.f ? o.z : av.z * o.z;
    o.w = o.w >= 0.f ? o.w : av.w * o.w;
    ((float4*)out)[i] = o;
}

extern "C" void kernel_launch(void* const* d_in, const int* in_sizes, int n_in,
                              void* d_out, int out_size, void* d_ws, size_t ws_size,
                              hipStream_t stream) {
    const float* x     = (const float*)d_in[0];
    const int*   eidx  = (const int*)d_in[1];   // [2, NE] int
    const float* ew    = (const float*)d_in[2];
    const float* Wm    = (const float*)d_in[3];
    const float* bias  = (const float*)d_in[4];
    const float* alpha = (const float*)d_in[5];
    const int* row = eidx;
    const int* col = eidx + NE;

    float* out  = (float*)d_out;
    float* deg  = (float*)d_ws;          // [NN]
    float* dinv = deg + NN;              // [NN]
    float* h    = dinv + NN;             // [NN*CD]

    hipMemsetAsync(d_out, 0, (size_t)NN * CD * sizeof(float), stream);
    init_deg   <<<(NN + 255) / 256, 256, 0, stream>>>(deg);
    deg_scatter<<<(NE + 255) / 256, 256, 0, stream>>>(col, ew, deg);
    rsqrt_deg  <<<(NN + 255) / 256, 256, 0, stream>>>(deg, dinv);
    gemm_xw    <<<(NN + 63) / 64, 256, 0, stream>>>(x, Wm, h);
    edge_scatter<<<NE / 4, 256, 0, stream>>>(row, col, ew, dinv, h, out);
    epilogue   <<<(NN * CD / 4 + 255) / 256, 256, 0, stream>>>(out, h, dinv, bias, alpha);
}

// Round 2
// 478.284 us; speedup vs baseline: 1.8120x; 1.8120x over previous
//
#include <hip/hip_runtime.h>

#define NN 50000
#define NE 800000
#define KD 256
#define CD 128

// ---------------------------------------------------- init: deg=1, cnt=0
__global__ __launch_bounds__(256) void init_deg_cnt(float* __restrict__ deg,
                                                    int* __restrict__ cnt) {
    int i = blockIdx.x * 256 + threadIdx.x;
    if (i < NN) { deg[i] = 1.0f; cnt[i] = 0; }
}

// ------------------------- per-edge: deg += ew @ col, histogram of col
__global__ __launch_bounds__(256) void deg_hist(const int* __restrict__ col,
                                                const float* __restrict__ ew,
                                                float* __restrict__ deg,
                                                int* __restrict__ cnt) {
    int e = blockIdx.x * 256 + threadIdx.x;
    if (e < NE) {
        int c = col[e];
        unsafeAtomicAdd(&deg[c], ew[e]);
        atomicAdd(&cnt[c], 1);
    }
}

// ---------------------------------------------------------------- rsqrt
__global__ __launch_bounds__(256) void rsqrt_deg(float* __restrict__ deg) {
    int i = blockIdx.x * 256 + threadIdx.x;
    if (i < NN) deg[i] = rsqrtf(deg[i]);  // deg >= 1 (self-loop), in place
}

// ------------------------- single-block exclusive scan of cnt -> start
__global__ __launch_bounds__(1024) void scan_kernel(const int* __restrict__ cnt,
                                                    int* __restrict__ start,
                                                    int* __restrict__ cursor) {
    __shared__ int part[1024];
    const int C = (NN + 1023) / 1024;  // 49
    int t = threadIdx.x;
    int base = t * C;
    int s = 0;
    for (int i = 0; i < C; i++) {
        int idx = base + i;
        if (idx < NN) s += cnt[idx];
    }
    part[t] = s;
    __syncthreads();
    // Hillis-Steele inclusive scan over 1024 partials
    for (int off = 1; off < 1024; off <<= 1) {
        int v = (t >= off) ? part[t - off] : 0;
        __syncthreads();
        part[t] += v;
        __syncthreads();
    }
    int off = part[t] - s;  // exclusive prefix of this thread's chunk
    for (int i = 0; i < C; i++) {
        int idx = base + i;
        if (idx < NN) {
            start[idx]  = off;
            cursor[idx] = off;
            off += cnt[idx];
        }
    }
    if (t == 1023) start[NN] = off;  // == NE
}

// -------- scatter edges into CSR order: meta[pos] = {row, dinv[row]*ew}
__global__ __launch_bounds__(256) void csr_scatter(const int* __restrict__ row,
                                                   const int* __restrict__ col,
                                                   const float* __restrict__ ew,
                                                   const float* __restrict__ dinv,
                                                   int* __restrict__ cursor,
                                                   int2* __restrict__ meta) {
    int e = blockIdx.x * 256 + threadIdx.x;
    if (e >= NE) return;
    int c = col[e];
    int r = row[e];
    int pos = atomicAdd(&cursor[c], 1);
    float f = dinv[r] * ew[e];
    meta[pos] = make_int2(r, __float_as_int(f));
}

// ------------------------------------------------- h = x @ W  (fp32 tiled)
// BM=64 nodes, BN=128 (all channels), BK=32. 256 threads, each 4x8 outputs.
__global__ __launch_bounds__(256) void gemm_xw(const float* __restrict__ x,
                                               const float* __restrict__ Wm,
                                               float* __restrict__ h) {
    __shared__ float As[64][33];
    __shared__ float Bs[32][132];

    const int tid = threadIdx.x;
    const int ty  = tid >> 4;
    const int tx  = tid & 15;
    const int row0 = blockIdx.x * 64;

    const int arow = tid >> 2;
    const int akq  = tid & 3;
    const int brow = tid >> 3;
    const int bcol = tid & 7;

    float acc[4][8];
#pragma unroll
    for (int i = 0; i < 4; i++)
#pragma unroll
        for (int j = 0; j < 8; j++) acc[i][j] = 0.0f;

    for (int kt = 0; kt < KD; kt += 32) {
        int anode = row0 + arow;
        float4 av0 = make_float4(0.f, 0.f, 0.f, 0.f), av1 = av0;
        if (anode < NN) {
            const float* xp = x + (size_t)anode * KD + kt;
            av0 = *(const float4*)(xp + akq * 4);
            av1 = *(const float4*)(xp + akq * 4 + 16);
        }
        As[arow][akq * 4 + 0]  = av0.x; As[arow][akq * 4 + 1]  = av0.y;
        As[arow][akq * 4 + 2]  = av0.z; As[arow][akq * 4 + 3]  = av0.w;
        As[arow][akq * 4 + 16] = av1.x; As[arow][akq * 4 + 17] = av1.y;
        As[arow][akq * 4 + 18] = av1.z; As[arow][akq * 4 + 19] = av1.w;
        const float* wp = Wm + (size_t)(kt + brow) * CD;
#pragma unroll
        for (int q = 0; q < 4; q++) {
            float4 bv = *(const float4*)(wp + (q * 8 + bcol) * 4);
            *(float4*)&Bs[brow][(q * 8 + bcol) * 4] = bv;
        }
        __syncthreads();
#pragma unroll
        for (int k = 0; k < 32; k++) {
            float aa[4];
#pragma unroll
            for (int i = 0; i < 4; i++) aa[i] = As[ty * 4 + i][k];
            float4 b0 = *(const float4*)&Bs[k][tx * 8];
            float4 b1 = *(const float4*)&Bs[k][tx * 8 + 4];
            float bb[8] = {b0.x, b0.y, b0.z, b0.w, b1.x, b1.y, b1.z, b1.w};
#pragma unroll
            for (int i = 0; i < 4; i++)
#pragma unroll
                for (int j = 0; j < 8; j++)
                    acc[i][j] = fmaf(aa[i], bb[j], acc[i][j]);
        }
        __syncthreads();
    }

#pragma unroll
    for (int i = 0; i < 4; i++) {
        int node = row0 + ty * 4 + i;
        if (node < NN) {
            float* hp = h + (size_t)node * CD + tx * 8;
            *(float4*)hp       = make_float4(acc[i][0], acc[i][1], acc[i][2], acc[i][3]);
            *(float4*)(hp + 4) = make_float4(acc[i][4], acc[i][5], acc[i][6], acc[i][7]);
        }
    }
}

// ---------- pull aggregation: one wave per destination node, fused epilogue
__global__ __launch_bounds__(256) void aggregate(const int* __restrict__ start,
                                                 const int2* __restrict__ meta,
                                                 const float* __restrict__ h,
                                                 const float* __restrict__ dinv,
                                                 const float* __restrict__ bias,
                                                 const float* __restrict__ alpha,
                                                 float* __restrict__ out) {
    int n = blockIdx.x * 4 + (threadIdx.x >> 6);
    if (n >= NN) return;
    n = __builtin_amdgcn_readfirstlane(n);
    const int lane = threadIdx.x & 63;
    const int s = __builtin_amdgcn_readfirstlane(start[n]);
    const int e = __builtin_amdgcn_readfirstlane(start[n + 1]);
    float a0 = 0.f, a1 = 0.f;
    for (int i = s; i < e; i++) {
        int2 m = meta[i];                 // wave-uniform -> scalar load
        float w = __int_as_float(m.y);    // dinv[row]*ew
        float2 v = *(const float2*)(h + (size_t)m.x * CD + lane * 2);
        a0 = fmaf(w, v.x, a0);
        a1 = fmaf(w, v.y, a1);
    }
    const float dc = dinv[n];
    float2 hv = *(const float2*)(h + (size_t)n * CD + lane * 2);
    const int ch = lane * 2;
    float o0 = dc * a0 + dc * dc * hv.x + bias[ch];
    float o1 = dc * a1 + dc * dc * hv.y + bias[ch + 1];
    o0 = o0 >= 0.f ? o0 : alpha[ch] * o0;
    o1 = o1 >= 0.f ? o1 : alpha[ch + 1] * o1;
    *(float2*)(out + (size_t)n * CD + ch) = make_float2(o0, o1);
}

extern "C" void kernel_launch(void* const* d_in, const int* in_sizes, int n_in,
                              void* d_out, int out_size, void* d_ws, size_t ws_size,
                              hipStream_t stream) {
    const float* x     = (const float*)d_in[0];
    const int*   eidx  = (const int*)d_in[1];   // [2, NE]
    const float* ew    = (const float*)d_in[2];
    const float* Wm    = (const float*)d_in[3];
    const float* bias  = (const float*)d_in[4];
    const float* alpha = (const float*)d_in[5];
    const int* row = eidx;
    const int* col = eidx + NE;

    float* out = (float*)d_out;

    // workspace layout (bytes)
    char* ws = (char*)d_ws;
    float* deg    = (float*)(ws);                     // NN floats (becomes dinv)
    int*   cnt    = (int*)(ws + 200000);              // NN ints
    int*   start  = (int*)(ws + 400000);              // NN+1 ints
    int*   cursor = (int*)(ws + 600004);              // NN ints
    int2*  meta   = (int2*)(ws + 800008);             // NE int2 (6.4 MB)
    float* h      = (float*)(ws + 800008 + (size_t)NE * 8 + 8);  // NN*CD floats

    init_deg_cnt<<<(NN + 255) / 256, 256, 0, stream>>>(deg, cnt);
    deg_hist    <<<(NE + 255) / 256, 256, 0, stream>>>(col, ew, deg, cnt);
    rsqrt_deg   <<<(NN + 255) / 256, 256, 0, stream>>>(deg);
    scan_kernel <<<1, 1024, 0, stream>>>(cnt, start, cursor);
    csr_scatter <<<(NE + 255) / 256, 256, 0, stream>>>(row, col, ew, deg, cursor, meta);
    gemm_xw     <<<(NN + 63) / 64, 256, 0, stream>>>(x, Wm, h);
    aggregate   <<<(NN + 3) / 4, 256, 0, stream>>>(start, meta, h, deg, bias, alpha, out);
}

// Round 3
// 347.372 us; speedup vs baseline: 2.4949x; 1.3769x over previous
//
#include <hip/hip_runtime.h>

#define NN 50000
#define NE 800000
#define KD 256
#define CD 128
#define NB 196          // scan blocks: 196*256 = 50176 >= NN

// ------------------------- per-edge: deg += ew @ col, histogram of col
__global__ __launch_bounds__(256) void deg_hist(const int* __restrict__ col,
                                                const float* __restrict__ ew,
                                                float* __restrict__ deg,
                                                int* __restrict__ cnt) {
    int e = blockIdx.x * 256 + threadIdx.x;
    if (e < NE) {
        int c = col[e];
        unsafeAtomicAdd(&deg[c], ew[e]);
        atomicAdd(&cnt[c], 1);
    }
}

// ------------------- scan phase 1: per-block exclusive scan + block total
__global__ __launch_bounds__(256) void scan_blocks(const int* __restrict__ cnt,
                                                   int* __restrict__ local,
                                                   int* __restrict__ partials) {
    __shared__ int sm[256];
    const int t = threadIdx.x;
    const int g = blockIdx.x * 256 + t;
    int v = (g < NN) ? cnt[g] : 0;
    sm[t] = v;
    __syncthreads();
#pragma unroll
    for (int off = 1; off < 256; off <<= 1) {
        int u = (t >= off) ? sm[t - off] : 0;
        __syncthreads();
        sm[t] += u;
        __syncthreads();
    }
    local[g] = sm[t] - v;                 // exclusive local prefix
    if (t == 255) partials[blockIdx.x] = sm[t];
}

// ------------------- scan phase 2: one block scans the NB partials
__global__ __launch_bounds__(256) void scan_partials(int* __restrict__ partials) {
    __shared__ int sm[256];
    const int t = threadIdx.x;
    int v = (t < NB) ? partials[t] : 0;
    sm[t] = v;
    __syncthreads();
#pragma unroll
    for (int off = 1; off < 256; off <<= 1) {
        int u = (t >= off) ? sm[t - off] : 0;
        __syncthreads();
        sm[t] += u;
        __syncthreads();
    }
    if (t < NB) partials[t] = sm[t] - v;  // exclusive
}

// ------- scan phase 3: apply block offset; also dinv = rsqrt(1+deg)
__global__ __launch_bounds__(256) void scan_apply(const int* __restrict__ local,
                                                  const int* __restrict__ partials,
                                                  const float* __restrict__ deg,
                                                  int* __restrict__ start,
                                                  int* __restrict__ cursor,
                                                  float* __restrict__ dinv) {
    const int g = blockIdx.x * 256 + threadIdx.x;
    if (g < NN) {
        int s = local[g] + partials[blockIdx.x];
        start[g]  = s;
        cursor[g] = s;
        dinv[g] = rsqrtf(1.0f + deg[g]);   // self-loop weight folded in
    }
    if (g == 0) start[NN] = NE;
}

// -------- scatter edges into CSR order: meta[pos] = {row, dinv[row]*ew}
__global__ __launch_bounds__(256) void csr_scatter(const int* __restrict__ row,
                                                   const int* __restrict__ col,
                                                   const float* __restrict__ ew,
                                                   const float* __restrict__ dinv,
                                                   int* __restrict__ cursor,
                                                   int2* __restrict__ meta) {
    int e = blockIdx.x * 256 + threadIdx.x;
    if (e >= NE) return;
    int c = col[e];
    int r = row[e];
    int pos = atomicAdd(&cursor[c], 1);
    float f = dinv[r] * ew[e];
    meta[pos] = make_int2(r, __float_as_int(f));
}

// ------------------------------------------------- h = x @ W  (fp32 tiled)
__global__ __launch_bounds__(256) void gemm_xw(const float* __restrict__ x,
                                               const float* __restrict__ Wm,
                                               float* __restrict__ h) {
    __shared__ float As[64][33];
    __shared__ float Bs[32][132];

    const int tid = threadIdx.x;
    const int ty  = tid >> 4;
    const int tx  = tid & 15;
    const int row0 = blockIdx.x * 64;

    const int arow = tid >> 2;
    const int akq  = tid & 3;
    const int brow = tid >> 3;
    const int bcol = tid & 7;

    float acc[4][8];
#pragma unroll
    for (int i = 0; i < 4; i++)
#pragma unroll
        for (int j = 0; j < 8; j++) acc[i][j] = 0.0f;

    for (int kt = 0; kt < KD; kt += 32) {
        int anode = row0 + arow;
        float4 av0 = make_float4(0.f, 0.f, 0.f, 0.f), av1 = av0;
        if (anode < NN) {
            const float* xp = x + (size_t)anode * KD + kt;
            av0 = *(const float4*)(xp + akq * 4);
            av1 = *(const float4*)(xp + akq * 4 + 16);
        }
        As[arow][akq * 4 + 0]  = av0.x; As[arow][akq * 4 + 1]  = av0.y;
        As[arow][akq * 4 + 2]  = av0.z; As[arow][akq * 4 + 3]  = av0.w;
        As[arow][akq * 4 + 16] = av1.x; As[arow][akq * 4 + 17] = av1.y;
        As[arow][akq * 4 + 18] = av1.z; As[arow][akq * 4 + 19] = av1.w;
        const float* wp = Wm + (size_t)(kt + brow) * CD;
#pragma unroll
        for (int q = 0; q < 4; q++) {
            float4 bv = *(const float4*)(wp + (q * 8 + bcol) * 4);
            *(float4*)&Bs[brow][(q * 8 + bcol) * 4] = bv;
        }
        __syncthreads();
#pragma unroll
        for (int k = 0; k < 32; k++) {
            float aa[4];
#pragma unroll
            for (int i = 0; i < 4; i++) aa[i] = As[ty * 4 + i][k];
            float4 b0 = *(const float4*)&Bs[k][tx * 8];
            float4 b1 = *(const float4*)&Bs[k][tx * 8 + 4];
            float bb[8] = {b0.x, b0.y, b0.z, b0.w, b1.x, b1.y, b1.z, b1.w};
#pragma unroll
            for (int i = 0; i < 4; i++)
#pragma unroll
                for (int j = 0; j < 8; j++)
                    acc[i][j] = fmaf(aa[i], bb[j], acc[i][j]);
        }
        __syncthreads();
    }

#pragma unroll
    for (int i = 0; i < 4; i++) {
        int node = row0 + ty * 4 + i;
        if (node < NN) {
            float* hp = h + (size_t)node * CD + tx * 8;
            *(float4*)hp       = make_float4(acc[i][0], acc[i][1], acc[i][2], acc[i][3]);
            *(float4*)(hp + 4) = make_float4(acc[i][4], acc[i][5], acc[i][6], acc[i][7]);
        }
    }
}

// ---------- pull aggregation: one wave per destination node, fused epilogue
__global__ __launch_bounds__(256) void aggregate(const int* __restrict__ start,
                                                 const int2* __restrict__ meta,
                                                 const float* __restrict__ h,
                                                 const float* __restrict__ dinv,
                                                 const float* __restrict__ bias,
                                                 const float* __restrict__ alpha,
                                                 float* __restrict__ out) {
    int n = blockIdx.x * 4 + (threadIdx.x >> 6);
    if (n >= NN) return;
    n = __builtin_amdgcn_readfirstlane(n);
    const int lane = threadIdx.x & 63;
    const int s = __builtin_amdgcn_readfirstlane(start[n]);
    const int e = __builtin_amdgcn_readfirstlane(start[n + 1]);
    float a0 = 0.f, a1 = 0.f;
    for (int i = s; i < e; i++) {
        int2 m = meta[i];                 // wave-uniform -> scalar load
        float w = __int_as_float(m.y);    // dinv[row]*ew
        float2 v = *(const float2*)(h + (size_t)m.x * CD + lane * 2);
        a0 = fmaf(w, v.x, a0);
        a1 = fmaf(w, v.y, a1);
    }
    const float dc = dinv[n];
    float2 hv = *(const float2*)(h + (size_t)n * CD + lane * 2);
    const int ch = lane * 2;
    float o0 = dc * a0 + dc * dc * hv.x + bias[ch];
    float o1 = dc * a1 + dc * dc * hv.y + bias[ch + 1];
    o0 = o0 >= 0.f ? o0 : alpha[ch] * o0;
    o1 = o1 >= 0.f ? o1 : alpha[ch + 1] * o1;
    *(float2*)(out + (size_t)n * CD + ch) = make_float2(o0, o1);
}

extern "C" void kernel_launch(void* const* d_in, const int* in_sizes, int n_in,
                              void* d_out, int out_size, void* d_ws, size_t ws_size,
                              hipStream_t stream) {
    const float* x     = (const float*)d_in[0];
    const int*   eidx  = (const int*)d_in[1];   // [2, NE]
    const float* ew    = (const float*)d_in[2];
    const float* Wm    = (const float*)d_in[3];
    const float* bias  = (const float*)d_in[4];
    const float* alpha = (const float*)d_in[5];
    const int* row = eidx;
    const int* col = eidx + NE;

    float* out = (float*)d_out;

    // workspace layout (bytes)
    char* ws = (char*)d_ws;
    float* deg      = (float*)(ws);                // NN f32, becomes base for dinv calc
    int*   cnt      = (int*)(ws + 200000);         // NN int
    int*   start    = (int*)(ws + 400000);         // NN+1 int
    int*   cursor   = (int*)(ws + 600008);         // NN int
    int*   local    = (int*)(ws + 800008);         // NB*256 int (50176)
    int*   partials = (int*)(ws + 1000712);        // NB int
    float* dinv     = (float*)(ws + 1001496);      // NN f32
    int2*  meta     = (int2*)(ws + 1201496);       // NE int2 (6.4 MB), 8B-aligned
    float* h        = (float*)(ws + 1201496 + (size_t)NE * 8);  // NN*CD f32 (25.6 MB)

    hipMemsetAsync(ws, 0, 400000, stream);         // deg + cnt
    deg_hist     <<<(NE + 255) / 256, 256, 0, stream>>>(col, ew, deg, cnt);
    scan_blocks  <<<NB, 256, 0, stream>>>(cnt, local, partials);
    scan_partials<<<1, 256, 0, stream>>>(partials);
    scan_apply   <<<NB, 256, 0, stream>>>(local, partials, deg, start, cursor, dinv);
    csr_scatter  <<<(NE + 255) / 256, 256, 0, stream>>>(row, col, ew, dinv, cursor, meta);
    gemm_xw      <<<(NN + 63) / 64, 256, 0, stream>>>(x, Wm, h);
    aggregate    <<<(NN + 3) / 4, 256, 0, stream>>>(start, meta, h, dinv, bias, alpha, out);
}

// Round 4
// 251.796 us; speedup vs baseline: 3.4419x; 1.3796x over previous
//
#include <hip/hip_runtime.h>

#define NN 50000
#define NE 800000
#define KD 256
#define CD 128
#define NB 196          // scan blocks: 196*256 = 50176 >= NN

typedef __attribute__((ext_vector_type(8))) short short8;
typedef __attribute__((ext_vector_type(4))) float floatx4;

__device__ inline unsigned short f2bf(float f) {
    unsigned u = __float_as_uint(f);
    unsigned r = (u + 0x7FFFu + ((u >> 16) & 1u)) >> 16;   // RNE
    return (unsigned short)r;
}
__device__ inline float bf2f_lo(unsigned u) { return __uint_as_float(u << 16); }
__device__ inline float bf2f_hi(unsigned u) { return __uint_as_float(u & 0xFFFF0000u); }

// ---- per-edge: single packed u64 atomic: count in [40:64), fixpoint sum ew in [0:40)
__global__ __launch_bounds__(256) void deg_hist(const int* __restrict__ col,
                                                const float* __restrict__ ew,
                                                unsigned long long* __restrict__ packed) {
    int e = blockIdx.x * 256 + threadIdx.x;
    if (e < NE) {
        unsigned long long p = (1ull << 40)
                             + (unsigned long long)(ew[e] * 4294967296.0f);
        atomicAdd(&packed[col[e]], p);
    }
}

// ------------------- scan phase 1: per-block exclusive scan + block total
__global__ __launch_bounds__(256) void scan_blocks(const unsigned long long* __restrict__ packed,
                                                   int* __restrict__ local,
                                                   int* __restrict__ partials) {
    __shared__ int sm[256];
    const int t = threadIdx.x;
    const int g = blockIdx.x * 256 + t;
    int v = (g < NN) ? (int)(packed[g] >> 40) : 0;
    sm[t] = v;
    __syncthreads();
#pragma unroll
    for (int off = 1; off < 256; off <<= 1) {
        int u = (t >= off) ? sm[t - off] : 0;
        __syncthreads();
        sm[t] += u;
        __syncthreads();
    }
    local[g] = sm[t] - v;
    if (t == 255) partials[blockIdx.x] = sm[t];
}

// ------------------- scan phase 2: one block scans the NB partials
__global__ __launch_bounds__(256) void scan_partials(int* __restrict__ partials) {
    __shared__ int sm[256];
    const int t = threadIdx.x;
    int v = (t < NB) ? partials[t] : 0;
    sm[t] = v;
    __syncthreads();
#pragma unroll
    for (int off = 1; off < 256; off <<= 1) {
        int u = (t >= off) ? sm[t - off] : 0;
        __syncthreads();
        sm[t] += u;
        __syncthreads();
    }
    if (t < NB) partials[t] = sm[t] - v;
}

// ------- scan phase 3: apply offsets; dinv = rsqrt(1 + sum_ew)
__global__ __launch_bounds__(256) void scan_apply(const int* __restrict__ local,
                                                  const int* __restrict__ partials,
                                                  const unsigned long long* __restrict__ packed,
                                                  int* __restrict__ start,
                                                  int* __restrict__ cursor,
                                                  float* __restrict__ dinv) {
    const int g = blockIdx.x * 256 + threadIdx.x;
    if (g < NN) {
        int s = local[g] + partials[blockIdx.x];
        start[g]  = s;
        cursor[g] = s;
        float degs = (float)(packed[g] & ((1ull << 40) - 1)) * (1.0f / 4294967296.0f);
        dinv[g] = rsqrtf(1.0f + degs);
    }
    if (g == 0) start[NN] = NE;
}

// -------- scatter edges into CSR order: meta[pos] = {row, dinv[row]*ew}
__global__ __launch_bounds__(256) void csr_scatter(const int* __restrict__ row,
                                                   const int* __restrict__ col,
                                                   const float* __restrict__ ew,
                                                   const float* __restrict__ dinv,
                                                   int* __restrict__ cursor,
                                                   int2* __restrict__ meta) {
    int e = blockIdx.x * 256 + threadIdx.x;
    if (e >= NE) return;
    int c = col[e];
    int r = row[e];
    int pos = atomicAdd(&cursor[c], 1);
    float f = dinv[r] * ew[e];
    meta[pos] = make_int2(r, __float_as_int(f));
}

// -------- W [K][N] fp32 -> Wt [N][K] bf16 (LDS tile transpose)
__global__ __launch_bounds__(256) void w_transpose(const float* __restrict__ W,
                                                   unsigned short* __restrict__ Wt) {
    __shared__ unsigned short t[32][33];
    const int bk = blockIdx.x * 32;      // k tile (0..7)
    const int bn = blockIdx.y * 32;      // n tile (0..3)
    const int tx = threadIdx.x & 31;
    const int ty = threadIdx.x >> 5;     // 0..7
#pragma unroll
    for (int i = 0; i < 32; i += 8)
        t[ty + i][tx] = f2bf(W[(size_t)(bk + ty + i) * CD + bn + tx]);  // t[k][n]
    __syncthreads();
#pragma unroll
    for (int i = 0; i < 32; i += 8)
        Wt[(size_t)(bn + ty + i) * KD + bk + tx] = t[tx][ty + i];       // Wt[n][k]
}

// ------------------- h = x @ W via bf16 MFMA; h stored bf16 [.][128]
// block: 256 thr = 4 waves; tile 64 rows x 128 ch; K staged 32/iter.
__global__ __launch_bounds__(256) void gemm_mfma(const float* __restrict__ x,
                                                 const unsigned short* __restrict__ Wt,
                                                 unsigned short* __restrict__ hb) {
    __shared__ unsigned short As[64][40];    // [row][k] +8 pad (16B-aligned rows)
    __shared__ unsigned short Bs[128][40];   // [n][k]  +8 pad

    const int tid  = threadIdx.x;
    const int wave = tid >> 6;
    const int lane = tid & 63;
    const int row0 = blockIdx.x * 64;
    const int m0   = wave * 16;
    const int lr   = lane & 15;
    const int quad = lane >> 4;

    const int ar = tid >> 2;          // A stage: row 0..63
    const int aq = tid & 3;           //          k-chunk 0..3 (8 el)
    const int bn = tid >> 1;          // B stage: n 0..127
    const int bh = (tid & 1) * 16;    //          k-chunk (16 el)

    floatx4 acc[8];
#pragma unroll
    for (int nt = 0; nt < 8; nt++) acc[nt] = (floatx4){0.f, 0.f, 0.f, 0.f};

    for (int kt = 0; kt < 8; kt++) {
        const int k0 = kt * 32;
        // ---- stage A (convert f32 -> bf16 in-register)
        union { short8 v; unsigned short u[8]; } av;
        const int gr = row0 + ar;
        if (gr < NN) {
            const float* xp = x + (size_t)gr * KD + k0 + aq * 8;
            float4 f0 = *(const float4*)xp;
            float4 f1 = *(const float4*)(xp + 4);
            av.u[0] = f2bf(f0.x); av.u[1] = f2bf(f0.y);
            av.u[2] = f2bf(f0.z); av.u[3] = f2bf(f0.w);
            av.u[4] = f2bf(f1.x); av.u[5] = f2bf(f1.y);
            av.u[6] = f2bf(f1.z); av.u[7] = f2bf(f1.w);
        } else {
            av.v = (short8){0,0,0,0,0,0,0,0};
        }
        *(short8*)&As[ar][aq * 8] = av.v;
        // ---- stage B from pre-transposed Wt (already bf16)
        const unsigned short* wp = Wt + (size_t)bn * KD + k0 + bh;
        *(short8*)&Bs[bn][bh]     = *(const short8*)wp;
        *(short8*)&Bs[bn][bh + 8] = *(const short8*)(wp + 8);
        __syncthreads();
        // ---- MFMA: 1 a-frag, 8 b-frags
        short8 af = *(const short8*)&As[m0 + lr][quad * 8];
#pragma unroll
        for (int nt = 0; nt < 8; nt++) {
            short8 bfr = *(const short8*)&Bs[nt * 16 + lr][quad * 8];
            acc[nt] = __builtin_amdgcn_mfma_f32_16x16x32_bf16(af, bfr, acc[nt], 0, 0, 0);
        }
        __syncthreads();
    }

    // ---- store C (bf16): row = row0+m0+quad*4+i, col = nt*16+lr
#pragma unroll
    for (int i = 0; i < 4; i++) {
        const int grow = row0 + m0 + quad * 4 + i;
        if (grow < NN) {
            unsigned short* hp = hb + (size_t)grow * CD + lr;
#pragma unroll
            for (int nt = 0; nt < 8; nt++)
                hp[nt * 16] = f2bf(acc[nt][i]);
        }
    }
}

// ---------- pull aggregation: one wave per node, bf16 h, 4-way ILP, fused epilogue
__global__ __launch_bounds__(256) void aggregate(const int* __restrict__ start,
                                                 const int2* __restrict__ meta,
                                                 const unsigned short* __restrict__ hb,
                                                 const float* __restrict__ dinv,
                                                 const float* __restrict__ bias,
                                                 const float* __restrict__ alpha,
                                                 float* __restrict__ out) {
    int n = blockIdx.x * 4 + (threadIdx.x >> 6);
    if (n >= NN) return;
    n = __builtin_amdgcn_readfirstlane(n);
    const int lane = threadIdx.x & 63;
    const int s = __builtin_amdgcn_readfirstlane(start[n]);
    const int e = __builtin_amdgcn_readfirstlane(start[n + 1]);

    float a0 = 0.f, a1 = 0.f, b0 = 0.f, b1 = 0.f;
    float c0 = 0.f, c1 = 0.f, d0 = 0.f, d1 = 0.f;
    int i = s;
    for (; i + 4 <= e; i += 4) {
        int2 m0 = meta[i], m1 = meta[i + 1], m2 = meta[i + 2], m3 = meta[i + 3];
        unsigned u0 = *(const unsigned*)(hb + (size_t)m0.x * CD + lane * 2);
        unsigned u1 = *(const unsigned*)(hb + (size_t)m1.x * CD + lane * 2);
        unsigned u2 = *(const unsigned*)(hb + (size_t)m2.x * CD + lane * 2);
        unsigned u3 = *(const unsigned*)(hb + (size_t)m3.x * CD + lane * 2);
        float w0 = __int_as_float(m0.y), w1 = __int_as_float(m1.y);
        float w2 = __int_as_float(m2.y), w3 = __int_as_float(m3.y);
        a0 = fmaf(w0, bf2f_lo(u0), a0); a1 = fmaf(w0, bf2f_hi(u0), a1);
        b0 = fmaf(w1, bf2f_lo(u1), b0); b1 = fmaf(w1, bf2f_hi(u1), b1);
        c0 = fmaf(w2, bf2f_lo(u2), c0); c1 = fmaf(w2, bf2f_hi(u2), c1);
        d0 = fmaf(w3, bf2f_lo(u3), d0); d1 = fmaf(w3, bf2f_hi(u3), d1);
    }
    for (; i < e; i++) {
        int2 m = meta[i];
        unsigned u = *(const unsigned*)(hb + (size_t)m.x * CD + lane * 2);
        float w = __int_as_float(m.y);
        a0 = fmaf(w, bf2f_lo(u), a0);
        a1 = fmaf(w, bf2f_hi(u), a1);
    }
    a0 += b0 + c0 + d0;
    a1 += b1 + c1 + d1;

    const float dc = dinv[n];
    unsigned us = *(const unsigned*)(hb + (size_t)n * CD + lane * 2);
    const int ch = lane * 2;
    float o0 = dc * a0 + dc * dc * bf2f_lo(us) + bias[ch];
    float o1 = dc * a1 + dc * dc * bf2f_hi(us) + bias[ch + 1];
    o0 = o0 >= 0.f ? o0 : alpha[ch] * o0;
    o1 = o1 >= 0.f ? o1 : alpha[ch + 1] * o1;
    *(float2*)(out + (size_t)n * CD + ch) = make_float2(o0, o1);
}

extern "C" void kernel_launch(void* const* d_in, const int* in_sizes, int n_in,
                              void* d_out, int out_size, void* d_ws, size_t ws_size,
                              hipStream_t stream) {
    const float* x     = (const float*)d_in[0];
    const int*   eidx  = (const int*)d_in[1];   // [2, NE]
    const float* ew    = (const float*)d_in[2];
    const float* Wm    = (const float*)d_in[3];
    const float* bias  = (const float*)d_in[4];
    const float* alpha = (const float*)d_in[5];
    const int* row = eidx;
    const int* col = eidx + NE;

    float* out = (float*)d_out;

    // workspace layout (bytes)
    char* ws = (char*)d_ws;
    unsigned long long* packed = (unsigned long long*)(ws);        // NN u64 (400000)
    int*   start    = (int*)(ws + 400000);                         // NN+1 int
    int*   cursor   = (int*)(ws + 600016);                         // NN int
    int*   local    = (int*)(ws + 800016);                         // 50176 int
    int*   partials = (int*)(ws + 1000720);                        // NB int
    float* dinv     = (float*)(ws + 1001504);                      // NN f32
    int2*  meta     = (int2*)(ws + 1201504);                       // NE int2 (6.4 MB)
    unsigned short* Wt = (unsigned short*)(ws + 7601504);          // 128*256 bf16
    unsigned short* hb = (unsigned short*)(ws + 7667040);          // 50176*128 bf16

    hipMemsetAsync(ws, 0, 400000, stream);                         // packed
    deg_hist     <<<(NE + 255) / 256, 256, 0, stream>>>(col, ew, packed);
    scan_blocks  <<<NB, 256, 0, stream>>>(packed, local, partials);
    scan_partials<<<1, 256, 0, stream>>>(partials);
    scan_apply   <<<NB, 256, 0, stream>>>(local, partials, packed, start, cursor, dinv);
    w_transpose  <<<dim3(8, 4), 256, 0, stream>>>(Wm, Wt);
    gemm_mfma    <<<(NN + 63) / 64, 256, 0, stream>>>(x, Wt, hb);
    csr_scatter  <<<(NE + 255) / 256, 256, 0, stream>>>(row, col, ew, dinv, cursor, meta);
    aggregate    <<<(NN + 3) / 4, 256, 0, stream>>>(start, meta, hb, dinv, bias, alpha, out);
}

// Round 5
// 216.773 us; speedup vs baseline: 3.9980x; 1.1616x over previous
//
#include <hip/hip_runtime.h>

#define NN 50000
#define NE 800000
#define KD 256
#define CD 128
#define NB 196          // scan blocks: 196*256 = 50176 >= NN

typedef __attribute__((ext_vector_type(8))) short short8;
typedef __attribute__((ext_vector_type(4))) float floatx4;

__device__ inline unsigned short f2bf(float f) {
    unsigned u = __float_as_uint(f);
    unsigned r = (u + 0x7FFFu + ((u >> 16) & 1u)) >> 16;   // RNE
    return (unsigned short)r;
}
__device__ inline float bf2f_lo(unsigned u) { return __uint_as_float(u << 16); }
__device__ inline float bf2f_hi(unsigned u) { return __uint_as_float(u & 0xFFFF0000u); }

// ---- per-edge: one packed u64 atomic: count in [40:64), fixpoint sum ew in [0:40).
// Returned old count == this edge's rank within its destination segment.
__global__ __launch_bounds__(256) void deg_hist(const int* __restrict__ col,
                                                const float* __restrict__ ew,
                                                unsigned long long* __restrict__ packed,
                                                unsigned short* __restrict__ rank) {
    int e = blockIdx.x * 256 + threadIdx.x;
    if (e < NE) {
        unsigned long long p = (1ull << 40)
                             + (unsigned long long)(ew[e] * 4294967296.0f);
        unsigned long long old = atomicAdd(&packed[col[e]], p);
        rank[e] = (unsigned short)(old >> 40);
    }
}

// ------------------- scan phase 1: per-block exclusive scan + block total
__global__ __launch_bounds__(256) void scan_blocks(const unsigned long long* __restrict__ packed,
                                                   int* __restrict__ local,
                                                   int* __restrict__ partials) {
    __shared__ int sm[256];
    const int t = threadIdx.x;
    const int g = blockIdx.x * 256 + t;
    int v = (g < NN) ? (int)(packed[g] >> 40) : 0;
    sm[t] = v;
    __syncthreads();
#pragma unroll
    for (int off = 1; off < 256; off <<= 1) {
        int u = (t >= off) ? sm[t - off] : 0;
        __syncthreads();
        sm[t] += u;
        __syncthreads();
    }
    local[g] = sm[t] - v;
    if (t == 255) partials[blockIdx.x] = sm[t];
}

// ------------------- scan phase 2: one block scans the NB partials
__global__ __launch_bounds__(256) void scan_partials(int* __restrict__ partials) {
    __shared__ int sm[256];
    const int t = threadIdx.x;
    int v = (t < NB) ? partials[t] : 0;
    sm[t] = v;
    __syncthreads();
#pragma unroll
    for (int off = 1; off < 256; off <<= 1) {
        int u = (t >= off) ? sm[t - off] : 0;
        __syncthreads();
        sm[t] += u;
        __syncthreads();
    }
    if (t < NB) partials[t] = sm[t] - v;
}

// ------- scan phase 3: apply offsets; dinv = rsqrt(1 + sum_ew)
__global__ __launch_bounds__(256) void scan_apply(const int* __restrict__ local,
                                                  const int* __restrict__ partials,
                                                  const unsigned long long* __restrict__ packed,
                                                  int* __restrict__ start,
                                                  float* __restrict__ dinv) {
    const int g = blockIdx.x * 256 + threadIdx.x;
    if (g < NN) {
        start[g] = local[g] + partials[blockIdx.x];
        float degs = (float)(packed[g] & ((1ull << 40) - 1)) * (1.0f / 4294967296.0f);
        dinv[g] = rsqrtf(1.0f + degs);
    }
    if (g == 0) start[NN] = NE;
}

// -------- atomic-free CSR placement: meta[start[col]+rank] = {row, dinv[row]*ew}
__global__ __launch_bounds__(256) void meta_write(const int* __restrict__ row,
                                                  const int* __restrict__ col,
                                                  const float* __restrict__ ew,
                                                  const unsigned short* __restrict__ rank,
                                                  const int* __restrict__ start,
                                                  const float* __restrict__ dinv,
                                                  int2* __restrict__ meta) {
    int e = blockIdx.x * 256 + threadIdx.x;
    if (e >= NE) return;
    int c = col[e];
    int r = row[e];
    int pos = start[c] + rank[e];
    float f = dinv[r] * ew[e];
    meta[pos] = make_int2(r, __float_as_int(f));
}

// -------- W [K][N] fp32 -> Wt [N][K] bf16 (LDS tile transpose)
__global__ __launch_bounds__(256) void w_transpose(const float* __restrict__ W,
                                                   unsigned short* __restrict__ Wt) {
    __shared__ unsigned short t[32][33];
    const int bk = blockIdx.x * 32;
    const int bn = blockIdx.y * 32;
    const int tx = threadIdx.x & 31;
    const int ty = threadIdx.x >> 5;
#pragma unroll
    for (int i = 0; i < 32; i += 8)
        t[ty + i][tx] = f2bf(W[(size_t)(bk + ty + i) * CD + bn + tx]);
    __syncthreads();
#pragma unroll
    for (int i = 0; i < 32; i += 8)
        Wt[(size_t)(bn + ty + i) * KD + bk + tx] = t[tx][ty + i];
}

// ------------------- h = x @ W via bf16 MFMA; h stored bf16 [.][128]
__global__ __launch_bounds__(256) void gemm_mfma(const float* __restrict__ x,
                                                 const unsigned short* __restrict__ Wt,
                                                 unsigned short* __restrict__ hb) {
    __shared__ unsigned short As[64][40];
    __shared__ unsigned short Bs[128][40];

    const int tid  = threadIdx.x;
    const int wave = tid >> 6;
    const int lane = tid & 63;
    const int row0 = blockIdx.x * 64;
    const int m0   = wave * 16;
    const int lr   = lane & 15;
    const int quad = lane >> 4;

    const int ar = tid >> 2;
    const int aq = tid & 3;
    const int bn = tid >> 1;
    const int bh = (tid & 1) * 16;

    floatx4 acc[8];
#pragma unroll
    for (int nt = 0; nt < 8; nt++) acc[nt] = (floatx4){0.f, 0.f, 0.f, 0.f};

    for (int kt = 0; kt < 8; kt++) {
        const int k0 = kt * 32;
        union { short8 v; unsigned short u[8]; } av;
        const int gr = row0 + ar;
        if (gr < NN) {
            const float* xp = x + (size_t)gr * KD + k0 + aq * 8;
            float4 f0 = *(const float4*)xp;
            float4 f1 = *(const float4*)(xp + 4);
            av.u[0] = f2bf(f0.x); av.u[1] = f2bf(f0.y);
            av.u[2] = f2bf(f0.z); av.u[3] = f2bf(f0.w);
            av.u[4] = f2bf(f1.x); av.u[5] = f2bf(f1.y);
            av.u[6] = f2bf(f1.z); av.u[7] = f2bf(f1.w);
        } else {
            av.v = (short8){0,0,0,0,0,0,0,0};
        }
        *(short8*)&As[ar][aq * 8] = av.v;
        const unsigned short* wp = Wt + (size_t)bn * KD + k0 + bh;
        *(short8*)&Bs[bn][bh]     = *(const short8*)wp;
        *(short8*)&Bs[bn][bh + 8] = *(const short8*)(wp + 8);
        __syncthreads();
        short8 af = *(const short8*)&As[m0 + lr][quad * 8];
#pragma unroll
        for (int nt = 0; nt < 8; nt++) {
            short8 bfr = *(const short8*)&Bs[nt * 16 + lr][quad * 8];
            acc[nt] = __builtin_amdgcn_mfma_f32_16x16x32_bf16(af, bfr, acc[nt], 0, 0, 0);
        }
        __syncthreads();
    }

#pragma unroll
    for (int i = 0; i < 4; i++) {
        const int grow = row0 + m0 + quad * 4 + i;
        if (grow < NN) {
            unsigned short* hp = hb + (size_t)grow * CD + lr;
#pragma unroll
            for (int nt = 0; nt < 8; nt++)
                hp[nt * 16] = f2bf(acc[nt][i]);
        }
    }
}

// ---------- pull aggregation: one wave per node, bf16 h, 4-way ILP, fused epilogue
__global__ __launch_bounds__(256) void aggregate(const int* __restrict__ start,
                                                 const int2* __restrict__ meta,
                                                 const unsigned short* __restrict__ hb,
                                                 const float* __restrict__ dinv,
                                                 const float* __restrict__ bias,
                                                 const float* __restrict__ alpha,
                                                 float* __restrict__ out) {
    int n = blockIdx.x * 4 + (threadIdx.x >> 6);
    if (n >= NN) return;
    n = __builtin_amdgcn_readfirstlane(n);
    const int lane = threadIdx.x & 63;
    const int s = __builtin_amdgcn_readfirstlane(start[n]);
    const int e = __builtin_amdgcn_readfirstlane(start[n + 1]);

    float a0 = 0.f, a1 = 0.f, b0 = 0.f, b1 = 0.f;
    float c0 = 0.f, c1 = 0.f, d0 = 0.f, d1 = 0.f;
    int i = s;
    for (; i + 4 <= e; i += 4) {
        int2 m0 = meta[i], m1 = meta[i + 1], m2 = meta[i + 2], m3 = meta[i + 3];
        unsigned u0 = *(const unsigned*)(hb + (size_t)m0.x * CD + lane * 2);
        unsigned u1 = *(const unsigned*)(hb + (size_t)m1.x * CD + lane * 2);
        unsigned u2 = *(const unsigned*)(hb + (size_t)m2.x * CD + lane * 2);
        unsigned u3 = *(const unsigned*)(hb + (size_t)m3.x * CD + lane * 2);
        float w0 = __int_as_float(m0.y), w1 = __int_as_float(m1.y);
        float w2 = __int_as_float(m2.y), w3 = __int_as_float(m3.y);
        a0 = fmaf(w0, bf2f_lo(u0), a0); a1 = fmaf(w0, bf2f_hi(u0), a1);
        b0 = fmaf(w1, bf2f_lo(u1), b0); b1 = fmaf(w1, bf2f_hi(u1), b1);
        c0 = fmaf(w2, bf2f_lo(u2), c0); c1 = fmaf(w2, bf2f_hi(u2), c1);
        d0 = fmaf(w3, bf2f_lo(u3), d0); d1 = fmaf(w3, bf2f_hi(u3), d1);
    }
    for (; i < e; i++) {
        int2 m = meta[i];
        unsigned u = *(const unsigned*)(hb + (size_t)m.x * CD + lane * 2);
        float w = __int_as_float(m.y);
        a0 = fmaf(w, bf2f_lo(u), a0);
        a1 = fmaf(w, bf2f_hi(u), a1);
    }
    a0 += b0 + c0 + d0;
    a1 += b1 + c1 + d1;

    const float dc = dinv[n];
    unsigned us = *(const unsigned*)(hb + (size_t)n * CD + lane * 2);
    const int ch = lane * 2;
    float o0 = dc * a0 + dc * dc * bf2f_lo(us) + bias[ch];
    float o1 = dc * a1 + dc * dc * bf2f_hi(us) + bias[ch + 1];
    o0 = o0 >= 0.f ? o0 : alpha[ch] * o0;
    o1 = o1 >= 0.f ? o1 : alpha[ch + 1] * o1;
    *(float2*)(out + (size_t)n * CD + ch) = make_float2(o0, o1);
}

extern "C" void kernel_launch(void* const* d_in, const int* in_sizes, int n_in,
                              void* d_out, int out_size, void* d_ws, size_t ws_size,
                              hipStream_t stream) {
    const float* x     = (const float*)d_in[0];
    const int*   eidx  = (const int*)d_in[1];   // [2, NE]
    const float* ew    = (const float*)d_in[2];
    const float* Wm    = (const float*)d_in[3];
    const float* bias  = (const float*)d_in[4];
    const float* alpha = (const float*)d_in[5];
    const int* row = eidx;
    const int* col = eidx + NE;

    float* out = (float*)d_out;

    // workspace layout (bytes)
    char* ws = (char*)d_ws;
    unsigned long long* packed = (unsigned long long*)(ws);      // NN u64 (400000)
    int*   start    = (int*)(ws + 400000);                       // NN+1 int
    int*   local    = (int*)(ws + 600016);                       // 50176 int
    int*   partials = (int*)(ws + 800720);                       // NB int
    float* dinv     = (float*)(ws + 801504);                     // NN f32
    unsigned short* rank = (unsigned short*)(ws + 1001504);      // NE u16 (1.6 MB)
    int2*  meta     = (int2*)(ws + 2601504);                     // NE int2 (6.4 MB), 8B-aligned
    unsigned short* Wt = (unsigned short*)(ws + 9001504);        // 128*256 bf16
    unsigned short* hb = (unsigned short*)(ws + 9067040);        // 50176*128 bf16

    hipMemsetAsync(ws, 0, 400000, stream);                       // packed
    deg_hist     <<<(NE + 255) / 256, 256, 0, stream>>>(col, ew, packed, rank);
    scan_blocks  <<<NB, 256, 0, stream>>>(packed, local, partials);
    scan_partials<<<1, 256, 0, stream>>>(partials);
    scan_apply   <<<NB, 256, 0, stream>>>(local, partials, packed, start, dinv);
    w_transpose  <<<dim3(8, 4), 256, 0, stream>>>(Wm, Wt);
    gemm_mfma    <<<(NN + 63) / 64, 256, 0, stream>>>(x, Wt, hb);
    meta_write   <<<(NE + 255) / 256, 256, 0, stream>>>(row, col, ew, rank, start, dinv, meta);
    aggregate    <<<(NN + 3) / 4, 256, 0, stream>>>(start, meta, hb, dinv, bias, alpha, out);
}

// Round 7
// 205.538 us; speedup vs baseline: 4.2165x; 1.0547x over previous
//
#include <hip/hip_runtime.h>

#define NN 50000
#define NE 800000
#define KD 256
#define CD 128
#define NB 196            // scan blocks: 196*256 = 50176 >= NN
#define GEMM_BLOCKS 782   // (NN+63)/64
#define HIST_BLOCKS 3125  // (NE+255)/256

typedef __attribute__((ext_vector_type(8))) short short8;
typedef __attribute__((ext_vector_type(4))) float floatx4;

__device__ inline unsigned short f2bf(float f) {
    unsigned u = __float_as_uint(f);
    unsigned r = (u + 0x7FFFu + ((u >> 16) & 1u)) >> 16;   // RNE
    return (unsigned short)r;
}
__device__ inline float bf2f_lo(unsigned u) { return __uint_as_float(u << 16); }
__device__ inline float bf2f_hi(unsigned u) { return __uint_as_float(u & 0xFFFF0000u); }

// ===== fused: GEMM tiles (blocks < GEMM_BLOCKS) + degree histogram (rest) =====
// The two roles use disjoint HW pipes (MFMA/LDS vs L2-atomic units) and overlap
// when co-resident on a CU.
__global__ __launch_bounds__(256) void fused_gemm_hist(
        const float* __restrict__ x, const unsigned short* __restrict__ Wt,
        unsigned short* __restrict__ hb,
        const int* __restrict__ col, const float* __restrict__ ew,
        unsigned long long* __restrict__ packed, unsigned short* __restrict__ rank) {
    __shared__ unsigned short As[64][40];
    __shared__ unsigned short Bs[128][40];

    if (blockIdx.x >= GEMM_BLOCKS) {
        // ---------------- histogram role: one packed u64 atomic per edge.
        // count in [40:64), fixpoint sum(ew) in [0:40); returned old count = rank.
        int e = (blockIdx.x - GEMM_BLOCKS) * 256 + threadIdx.x;
        if (e < NE) {
            unsigned long long p = (1ull << 40)
                                 + (unsigned long long)(ew[e] * 4294967296.0f);
            unsigned long long old = atomicAdd(&packed[col[e]], p);
            rank[e] = (unsigned short)(old >> 40);
        }
        return;
    }

    // ---------------- GEMM role: h = bf16(x) @ Wt^T, 64 rows x 128 ch / block
    const int tid  = threadIdx.x;
    const int wave = tid >> 6;
    const int lane = tid & 63;
    const int row0 = blockIdx.x * 64;
    const int m0   = wave * 16;
    const int lr   = lane & 15;
    const int quad = lane >> 4;

    const int ar = tid >> 2;
    const int aq = tid & 3;
    const int bn = tid >> 1;
    const int bh = (tid & 1) * 16;

    floatx4 acc[8];
#pragma unroll
    for (int nt = 0; nt < 8; nt++) acc[nt] = (floatx4){0.f, 0.f, 0.f, 0.f};

    for (int kt = 0; kt < 8; kt++) {
        const int k0 = kt * 32;
        union { short8 v; unsigned short u[8]; } av;
        const int gr = row0 + ar;
        if (gr < NN) {
            const float* xp = x + (size_t)gr * KD + k0 + aq * 8;
            float4 f0 = *(const float4*)xp;
            float4 f1 = *(const float4*)(xp + 4);
            av.u[0] = f2bf(f0.x); av.u[1] = f2bf(f0.y);
            av.u[2] = f2bf(f0.z); av.u[3] = f2bf(f0.w);
            av.u[4] = f2bf(f1.x); av.u[5] = f2bf(f1.y);
            av.u[6] = f2bf(f1.z); av.u[7] = f2bf(f1.w);
        } else {
            av.v = (short8){0,0,0,0,0,0,0,0};
        }
        *(short8*)&As[ar][aq * 8] = av.v;
        const unsigned short* wp = Wt + (size_t)bn * KD + k0 + bh;
        *(short8*)&Bs[bn][bh]     = *(const short8*)wp;
        *(short8*)&Bs[bn][bh + 8] = *(const short8*)(wp + 8);
        __syncthreads();
        short8 af = *(const short8*)&As[m0 + lr][quad * 8];
#pragma unroll
        for (int nt = 0; nt < 8; nt++) {
            short8 bfr = *(const short8*)&Bs[nt * 16 + lr][quad * 8];
            acc[nt] = __builtin_amdgcn_mfma_f32_16x16x32_bf16(af, bfr, acc[nt], 0, 0, 0);
        }
        __syncthreads();
    }

#pragma unroll
    for (int i = 0; i < 4; i++) {
        const int grow = row0 + m0 + quad * 4 + i;
        if (grow < NN) {
            unsigned short* hp = hb + (size_t)grow * CD + lr;
#pragma unroll
            for (int nt = 0; nt < 8; nt++)
                hp[nt * 16] = f2bf(acc[nt][i]);
        }
    }
}

// ------------------- scan phase 1: per-block exclusive scan + block total
__global__ __launch_bounds__(256) void scan_blocks(const unsigned long long* __restrict__ packed,
                                                   int* __restrict__ local,
                                                   int* __restrict__ partials) {
    __shared__ int sm[256];
    const int t = threadIdx.x;
    const int g = blockIdx.x * 256 + t;
    int v = (g < NN) ? (int)(packed[g] >> 40) : 0;
    sm[t] = v;
    __syncthreads();
#pragma unroll
    for (int off = 1; off < 256; off <<= 1) {
        int u = (t >= off) ? sm[t - off] : 0;
        __syncthreads();
        sm[t] += u;
        __syncthreads();
    }
    local[g] = sm[t] - v;
    if (t == 255) partials[blockIdx.x] = sm[t];   // block total
}

// ---- scan phase 2 (fused): base = sum(partials[0..b)) via tree-reduce, then apply
__global__ __launch_bounds__(256) void scan_apply(const int* __restrict__ local,
                                                  const int* __restrict__ partials,
                                                  const unsigned long long* __restrict__ packed,
                                                  int* __restrict__ start,
                                                  float* __restrict__ dinv) {
    __shared__ int sm[256];
    const int t = threadIdx.x;
    const int b = blockIdx.x;
    sm[t] = (t < b) ? partials[t] : 0;    // b <= 195 < 256
    __syncthreads();
#pragma unroll
    for (int off = 128; off > 0; off >>= 1) {
        if (t < off) sm[t] += sm[t + off];
        __syncthreads();
    }
    const int base = sm[0];
    const int g = b * 256 + t;
    if (g < NN) {
        start[g] = local[g] + base;
        float degs = (float)(packed[g] & ((1ull << 40) - 1)) * (1.0f / 4294967296.0f);
        dinv[g] = rsqrtf(1.0f + degs);
    }
    if (g == 0) start[NN] = NE;
}

// -------- atomic-free CSR placement: meta[start[col]+rank] = {row, dinv[row]*ew}
__global__ __launch_bounds__(256) void meta_write(const int* __restrict__ row,
                                                  const int* __restrict__ col,
                                                  const float* __restrict__ ew,
                                                  const unsigned short* __restrict__ rank,
                                                  const int* __restrict__ start,
                                                  const float* __restrict__ dinv,
                                                  int2* __restrict__ meta) {
    int e = blockIdx.x * 256 + threadIdx.x;
    if (e >= NE) return;
    int c = col[e];
    int r = row[e];
    int pos = start[c] + rank[e];
    float f = dinv[r] * ew[e];
    meta[pos] = make_int2(r, __float_as_int(f));
}

// -------- W [K][N] fp32 -> Wt [N][K] bf16 (LDS tile transpose)
__global__ __launch_bounds__(256) void w_transpose(const float* __restrict__ W,
                                                   unsigned short* __restrict__ Wt) {
    __shared__ unsigned short t[32][33];
    const int bk = blockIdx.x * 32;
    const int bn = blockIdx.y * 32;
    const int tx = threadIdx.x & 31;
    const int ty = threadIdx.x >> 5;
#pragma unroll
    for (int i = 0; i < 32; i += 8)
        t[ty + i][tx] = f2bf(W[(size_t)(bk + ty + i) * CD + bn + tx]);
    __syncthreads();
#pragma unroll
    for (int i = 0; i < 32; i += 8)
        Wt[(size_t)(bn + ty + i) * KD + bk + tx] = t[tx][ty + i];
}

// ---------- pull aggregation: one wave per node, bf16 h, 8-way ILP, fused epilogue
__global__ __launch_bounds__(256) void aggregate(const int* __restrict__ start,
                                                 const int2* __restrict__ meta,
                                                 const unsigned short* __restrict__ hb,
                                                 const float* __restrict__ dinv,
                                                 const float* __restrict__ bias,
                                                 const float* __restrict__ alpha,
                                                 float* __restrict__ out) {
    int n = blockIdx.x * 4 + (threadIdx.x >> 6);
    if (n >= NN) return;
    n = __builtin_amdgcn_readfirstlane(n);
    const int lane = threadIdx.x & 63;
    const int s = __builtin_amdgcn_readfirstlane(start[n]);
    const int e = __builtin_amdgcn_readfirstlane(start[n + 1]);

    float A0[8], A1[8];
#pragma unroll
    for (int j = 0; j < 8; j++) { A0[j] = 0.f; A1[j] = 0.f; }

    int i = s;
    for (; i + 8 <= e; i += 8) {
        int2 m[8];
        unsigned u[8];
#pragma unroll
        for (int j = 0; j < 8; j++) m[j] = meta[i + j];
#pragma unroll
        for (int j = 0; j < 8; j++)
            u[j] = *(const unsigned*)(hb + (size_t)m[j].x * CD + lane * 2);
#pragma unroll
        for (int j = 0; j < 8; j++) {
            float w = __int_as_float(m[j].y);
            A0[j] = fmaf(w, bf2f_lo(u[j]), A0[j]);
            A1[j] = fmaf(w, bf2f_hi(u[j]), A1[j]);
        }
    }
    for (; i < e; i++) {
        int2 m = meta[i];
        unsigned u = *(const unsigned*)(hb + (size_t)m.x * CD + lane * 2);
        float w = __int_as_float(m.y);
        A0[0] = fmaf(w, bf2f_lo(u), A0[0]);
        A1[0] = fmaf(w, bf2f_hi(u), A1[0]);
    }
#pragma unroll
    for (int j = 1; j < 8; j++) { A0[0] += A0[j]; A1[0] += A1[j]; }

    const float dc = dinv[n];
    unsigned us = *(const unsigned*)(hb + (size_t)n * CD + lane * 2);
    const int ch = lane * 2;
    float o0 = dc * A0[0] + dc * dc * bf2f_lo(us) + bias[ch];
    float o1 = dc * A1[0] + dc * dc * bf2f_hi(us) + bias[ch + 1];
    o0 = o0 >= 0.f ? o0 : alpha[ch] * o0;
    o1 = o1 >= 0.f ? o1 : alpha[ch + 1] * o1;
    *(float2*)(out + (size_t)n * CD + ch) = make_float2(o0, o1);
}

extern "C" void kernel_launch(void* const* d_in, const int* in_sizes, int n_in,
                              void* d_out, int out_size, void* d_ws, size_t ws_size,
                              hipStream_t stream) {
    const float* x     = (const float*)d_in[0];
    const int*   eidx  = (const int*)d_in[1];   // [2, NE]
    const float* ew    = (const float*)d_in[2];
    const float* Wm    = (const float*)d_in[3];
    const float* bias  = (const float*)d_in[4];
    const float* alpha = (const float*)d_in[5];
    const int* row = eidx;
    const int* col = eidx + NE;

    float* out = (float*)d_out;

    // workspace layout (bytes)
    char* ws = (char*)d_ws;
    unsigned long long* packed = (unsigned long long*)(ws);      // NN u64 (400000)
    int*   start    = (int*)(ws + 400000);                       // NN+1 int
    int*   local    = (int*)(ws + 600016);                       // 50176 int
    int*   partials = (int*)(ws + 800720);                       // NB int
    float* dinv     = (float*)(ws + 801504);                     // NN f32
    unsigned short* rank = (unsigned short*)(ws + 1001504);      // NE u16 (1.6 MB)
    int2*  meta     = (int2*)(ws + 2601504);                     // NE int2 (6.4 MB)
    unsigned short* Wt = (unsigned short*)(ws + 9001504);        // 128*256 bf16
    unsigned short* hb = (unsigned short*)(ws + 9067040);        // 50176*128 bf16

    hipMemsetAsync(ws, 0, 400000, stream);                       // packed
    w_transpose   <<<dim3(8, 4), 256, 0, stream>>>(Wm, Wt);
    fused_gemm_hist<<<GEMM_BLOCKS + HIST_BLOCKS, 256, 0, stream>>>(
                        x, Wt, hb, col, ew, packed, rank);
    scan_blocks   <<<NB, 256, 0, stream>>>(packed, local, partials);
    scan_apply    <<<NB, 256, 0, stream>>>(local, partials, packed, start, dinv);
    meta_write    <<<(NE + 255) / 256, 256, 0, stream>>>(row, col, ew, rank, start, dinv, meta);
    aggregate     <<<(NN + 3) / 4, 256, 0, stream>>>(start, meta, hb, dinv, bias, alpha, out);
}

// Round 8
// 203.292 us; speedup vs baseline: 4.2631x; 1.0110x over previous
//
#include <hip/hip_runtime.h>

#define NN 50000
#define NE 800000
#define KD 256
#define CD 128
#define NB 196            // scan blocks: 196*256 = 50176 >= NN
#define GEMM_BLOCKS 782   // (NN+63)/64
#define HIST_BLOCKS 3125  // (NE+255)/256

typedef __attribute__((ext_vector_type(8))) short short8;
typedef __attribute__((ext_vector_type(4))) float floatx4;

__device__ inline unsigned short f2bf(float f) {
    unsigned u = __float_as_uint(f);
    unsigned r = (u + 0x7FFFu + ((u >> 16) & 1u)) >> 16;   // RNE
    return (unsigned short)r;
}
__device__ inline float bf2f_lo(unsigned u) { return __uint_as_float(u << 16); }
__device__ inline float bf2f_hi(unsigned u) { return __uint_as_float(u & 0xFFFF0000u); }

// ===== fused: GEMM tiles (blocks < GEMM_BLOCKS) + degree histogram (rest) =====
// Histogram uses 4 shadow copies (copy = hist-block & 3) to cut same-address
// atomic chain depth 16 -> 4. count in [40:64), fixpoint sum(ew) in [0:40).
__global__ __launch_bounds__(256) void fused_gemm_hist(
        const float* __restrict__ x, const unsigned short* __restrict__ Wt,
        unsigned short* __restrict__ hb,
        const int* __restrict__ col, const float* __restrict__ ew,
        unsigned long long* __restrict__ packedAll, unsigned short* __restrict__ rank) {
    __shared__ unsigned short As[64][40];
    __shared__ unsigned short Bs[128][40];

    if (blockIdx.x >= GEMM_BLOCKS) {
        const int hblk = blockIdx.x - GEMM_BLOCKS;
        int e = hblk * 256 + threadIdx.x;
        if (e < NE) {
            unsigned long long* packed = packedAll + (size_t)(hblk & 3) * NN;
            unsigned long long p = (1ull << 40)
                                 + (unsigned long long)(ew[e] * 4294967296.0f);
            unsigned long long old = atomicAdd(&packed[col[e]], p);
            rank[e] = (unsigned short)(old >> 40);   // rank within copy
        }
        return;
    }

    // ---------------- GEMM role: h = bf16(x) @ Wt^T, 64 rows x 128 ch / block
    const int tid  = threadIdx.x;
    const int wave = tid >> 6;
    const int lane = tid & 63;
    const int row0 = blockIdx.x * 64;
    const int m0   = wave * 16;
    const int lr   = lane & 15;
    const int quad = lane >> 4;

    const int ar = tid >> 2;
    const int aq = tid & 3;
    const int bn = tid >> 1;
    const int bh = (tid & 1) * 16;

    floatx4 acc[8];
#pragma unroll
    for (int nt = 0; nt < 8; nt++) acc[nt] = (floatx4){0.f, 0.f, 0.f, 0.f};

    for (int kt = 0; kt < 8; kt++) {
        const int k0 = kt * 32;
        union { short8 v; unsigned short u[8]; } av;
        const int gr = row0 + ar;
        if (gr < NN) {
            const float* xp = x + (size_t)gr * KD + k0 + aq * 8;
            float4 f0 = *(const float4*)xp;
            float4 f1 = *(const float4*)(xp + 4);
            av.u[0] = f2bf(f0.x); av.u[1] = f2bf(f0.y);
            av.u[2] = f2bf(f0.z); av.u[3] = f2bf(f0.w);
            av.u[4] = f2bf(f1.x); av.u[5] = f2bf(f1.y);
            av.u[6] = f2bf(f1.z); av.u[7] = f2bf(f1.w);
        } else {
            av.v = (short8){0,0,0,0,0,0,0,0};
        }
        *(short8*)&As[ar][aq * 8] = av.v;
        const unsigned short* wp = Wt + (size_t)bn * KD + k0 + bh;
        *(short8*)&Bs[bn][bh]     = *(const short8*)wp;
        *(short8*)&Bs[bn][bh + 8] = *(const short8*)(wp + 8);
        __syncthreads();
        short8 af = *(const short8*)&As[m0 + lr][quad * 8];
#pragma unroll
        for (int nt = 0; nt < 8; nt++) {
            short8 bfr = *(const short8*)&Bs[nt * 16 + lr][quad * 8];
            acc[nt] = __builtin_amdgcn_mfma_f32_16x16x32_bf16(af, bfr, acc[nt], 0, 0, 0);
        }
        __syncthreads();
    }

#pragma unroll
    for (int i = 0; i < 4; i++) {
        const int grow = row0 + m0 + quad * 4 + i;
        if (grow < NN) {
            unsigned short* hp = hb + (size_t)grow * CD + lr;
#pragma unroll
            for (int nt = 0; nt < 8; nt++)
                hp[nt * 16] = f2bf(acc[nt][i]);
        }
    }
}

// ------------------- scan phase 1: per-block exclusive scan of total counts
__global__ __launch_bounds__(256) void scan_blocks(const unsigned long long* __restrict__ packedAll,
                                                   int* __restrict__ local,
                                                   int* __restrict__ partials) {
    __shared__ int sm[256];
    const int t = threadIdx.x;
    const int g = blockIdx.x * 256 + t;
    int v = 0;
    if (g < NN) {
#pragma unroll
        for (int c = 0; c < 4; c++)
            v += (int)(packedAll[(size_t)c * NN + g] >> 40);
    }
    sm[t] = v;
    __syncthreads();
#pragma unroll
    for (int off = 1; off < 256; off <<= 1) {
        int u = (t >= off) ? sm[t - off] : 0;
        __syncthreads();
        sm[t] += u;
        __syncthreads();
    }
    local[g] = sm[t] - v;
    if (t == 255) partials[blockIdx.x] = sm[t];
}

// ---- scan phase 2: base via tree-reduce; emit start, base4 (per-copy), dinv
__global__ __launch_bounds__(256) void scan_apply(const int* __restrict__ local,
                                                  const int* __restrict__ partials,
                                                  const unsigned long long* __restrict__ packedAll,
                                                  int* __restrict__ start,
                                                  int4* __restrict__ base4,
                                                  float* __restrict__ dinv) {
    __shared__ int sm[256];
    const int t = threadIdx.x;
    const int b = blockIdx.x;
    sm[t] = (t < b) ? partials[t] : 0;    // b <= 195 < 256
    __syncthreads();
#pragma unroll
    for (int off = 128; off > 0; off >>= 1) {
        if (t < off) sm[t] += sm[t + off];
        __syncthreads();
    }
    const int base = sm[0];
    const int g = b * 256 + t;
    if (g < NN) {
        int cc[4];
        unsigned long long lowsum = 0;
#pragma unroll
        for (int c = 0; c < 4; c++) {
            unsigned long long p = packedAll[(size_t)c * NN + g];
            cc[c] = (int)(p >> 40);
            lowsum += p & ((1ull << 40) - 1);
        }
        const int s = local[g] + base;
        start[g] = s;
        base4[g] = make_int4(s, s + cc[0], s + cc[0] + cc[1], s + cc[0] + cc[1] + cc[2]);
        float degs = (float)lowsum * (1.0f / 4294967296.0f);
        dinv[g] = rsqrtf(1.0f + degs);
    }
    if (g == 0) start[NN] = NE;
}

// -------- atomic-free CSR placement: meta[base4[col][copy]+rank] = {bf16 w | u16 row}
__global__ __launch_bounds__(256) void meta_write(const int* __restrict__ row,
                                                  const int* __restrict__ col,
                                                  const float* __restrict__ ew,
                                                  const unsigned short* __restrict__ rank,
                                                  const int4* __restrict__ base4,
                                                  const float* __restrict__ dinv,
                                                  unsigned* __restrict__ meta) {
    int e = blockIdx.x * 256 + threadIdx.x;
    if (e >= NE) return;
    const int copy = blockIdx.x & 3;            // == (e>>8)&3, wave-uniform
    int c = col[e];
    int r = row[e];
    int4 b4 = base4[c];
    int base = (copy == 0) ? b4.x : (copy == 1) ? b4.y : (copy == 2) ? b4.z : b4.w;
    int pos = base + rank[e];
    unsigned short wbf = f2bf(dinv[r] * ew[e]);
    meta[pos] = ((unsigned)wbf << 16) | (unsigned)r;
}

// -------- W [K][N] fp32 -> Wt [N][K] bf16 (LDS tile transpose)
__global__ __launch_bounds__(256) void w_transpose(const float* __restrict__ W,
                                                   unsigned short* __restrict__ Wt) {
    __shared__ unsigned short t[32][33];
    const int bk = blockIdx.x * 32;
    const int bn = blockIdx.y * 32;
    const int tx = threadIdx.x & 31;
    const int ty = threadIdx.x >> 5;
#pragma unroll
    for (int i = 0; i < 32; i += 8)
        t[ty + i][tx] = f2bf(W[(size_t)(bk + ty + i) * CD + bn + tx]);
    __syncthreads();
#pragma unroll
    for (int i = 0; i < 32; i += 8)
        Wt[(size_t)(bn + ty + i) * KD + bk + tx] = t[tx][ty + i];
}

// ---------- pull aggregation: one wave per node, bf16 h, 8-way ILP, fused epilogue
__global__ __launch_bounds__(256) void aggregate(const int* __restrict__ start,
                                                 const unsigned* __restrict__ meta,
                                                 const unsigned short* __restrict__ hb,
                                                 const float* __restrict__ dinv,
                                                 const float* __restrict__ bias,
                                                 const float* __restrict__ alpha,
                                                 float* __restrict__ out) {
    int n = blockIdx.x * 4 + (threadIdx.x >> 6);
    if (n >= NN) return;
    n = __builtin_amdgcn_readfirstlane(n);
    const int lane = threadIdx.x & 63;
    const int s = __builtin_amdgcn_readfirstlane(start[n]);
    const int e = __builtin_amdgcn_readfirstlane(start[n + 1]);

    float A0[8], A1[8];
#pragma unroll
    for (int j = 0; j < 8; j++) { A0[j] = 0.f; A1[j] = 0.f; }

    int i = s;
    for (; i + 8 <= e; i += 8) {
        unsigned m[8], u[8];
#pragma unroll
        for (int j = 0; j < 8; j++) m[j] = meta[i + j];
#pragma unroll
        for (int j = 0; j < 8; j++)
            u[j] = *(const unsigned*)(hb + (size_t)(m[j] & 0xFFFFu) * CD + lane * 2);
#pragma unroll
        for (int j = 0; j < 8; j++) {
            float w = __uint_as_float(m[j] & 0xFFFF0000u);
            A0[j] = fmaf(w, bf2f_lo(u[j]), A0[j]);
            A1[j] = fmaf(w, bf2f_hi(u[j]), A1[j]);
        }
    }
    for (; i < e; i++) {
        unsigned m = meta[i];
        unsigned u = *(const unsigned*)(hb + (size_t)(m & 0xFFFFu) * CD + lane * 2);
        float w = __uint_as_float(m & 0xFFFF0000u);
        A0[0] = fmaf(w, bf2f_lo(u), A0[0]);
        A1[0] = fmaf(w, bf2f_hi(u), A1[0]);
    }
#pragma unroll
    for (int j = 1; j < 8; j++) { A0[0] += A0[j]; A1[0] += A1[j]; }

    const float dc = dinv[n];
    unsigned us = *(const unsigned*)(hb + (size_t)n * CD + lane * 2);
    const int ch = lane * 2;
    float o0 = dc * A0[0] + dc * dc * bf2f_lo(us) + bias[ch];
    float o1 = dc * A1[0] + dc * dc * bf2f_hi(us) + bias[ch + 1];
    o0 = o0 >= 0.f ? o0 : alpha[ch] * o0;
    o1 = o1 >= 0.f ? o1 : alpha[ch + 1] * o1;
    *(float2*)(out + (size_t)n * CD + ch) = make_float2(o0, o1);
}

extern "C" void kernel_launch(void* const* d_in, const int* in_sizes, int n_in,
                              void* d_out, int out_size, void* d_ws, size_t ws_size,
                              hipStream_t stream) {
    const float* x     = (const float*)d_in[0];
    const int*   eidx  = (const int*)d_in[1];   // [2, NE]
    const float* ew    = (const float*)d_in[2];
    const float* Wm    = (const float*)d_in[3];
    const float* bias  = (const float*)d_in[4];
    const float* alpha = (const float*)d_in[5];
    const int* row = eidx;
    const int* col = eidx + NE;

    float* out = (float*)d_out;

    // workspace layout (bytes)
    char* ws = (char*)d_ws;
    unsigned long long* packedAll = (unsigned long long*)(ws);   // 4*NN u64 (1.6 MB)
    int*   start    = (int*)(ws + 1600000);                      // NN+1 int
    int*   local    = (int*)(ws + 1800016);                      // 50176 int
    int*   partials = (int*)(ws + 2000720);                      // NB int
    float* dinv     = (float*)(ws + 2001504);                    // NN f32
    unsigned short* rank = (unsigned short*)(ws + 2201504);      // NE u16 (1.6 MB)
    int4*  base4    = (int4*)(ws + 3801504);                     // NN int4 (800 KB), 16B-aligned
    unsigned* meta  = (unsigned*)(ws + 4601504);                 // NE u32 (3.2 MB)
    unsigned short* Wt = (unsigned short*)(ws + 7801504);        // 128*256 bf16
    unsigned short* hb = (unsigned short*)(ws + 7867040);        // 50176*128 bf16

    hipMemsetAsync(ws, 0, 1600000, stream);                      // 4 shadow histograms
    w_transpose   <<<dim3(8, 4), 256, 0, stream>>>(Wm, Wt);
    fused_gemm_hist<<<GEMM_BLOCKS + HIST_BLOCKS, 256, 0, stream>>>(
                        x, Wt, hb, col, ew, packedAll, rank);
    scan_blocks   <<<NB, 256, 0, stream>>>(packedAll, local, partials);
    scan_apply    <<<NB, 256, 0, stream>>>(local, partials, packedAll, start, base4, dinv);
    meta_write    <<<(NE + 255) / 256, 256, 0, stream>>>(row, col, ew, rank, base4, dinv, meta);
    aggregate     <<<(NN + 3) / 4, 256, 0, stream>>>(start, meta, hb, dinv, bias, alpha, out);
}